// Round 1
// baseline (559.545 us; speedup 1.0000x reference)
//
#include <hip/hip_runtime.h>

#define N_NODES 80000
#define N_EDGES 64000
#define NB      32
#define NG      2500
#define NA      50
#define EDIM    16
#define FIN     159      // H2(64) + AF(95)
#define HG      128
#define RICOLS  2688     // 21 blocks of 128: 18 root(t,k) + 3 init(k)

// ---------------- root GEMM: out[n,:] = in[n,:] @ W(64x64) + bias ----------------
__global__ __launch_bounds__(256) void root_gemm(const float* __restrict__ in,
    const float* __restrict__ w, const float* __restrict__ bias, float* __restrict__ out)
{
    __shared__ float At[64 * 65];   // At[c*65 + r]
    __shared__ float Wl[64 * 64];   // [i*64 + o]
    __shared__ float bl[64];
    const int tid = threadIdx.x;
    const int r0 = blockIdx.x * 64;
    for (int s = tid; s < 4096; s += 256) { int r = s >> 6, c = s & 63; At[c * 65 + r] = in[(r0 + r) * 64 + c]; }
    for (int s = tid; s < 4096; s += 256) Wl[s] = w[s];
    if (tid < 64) bl[tid] = bias[tid];
    __syncthreads();
    const int tr = tid >> 4, tc = tid & 15;
    float acc[4][4] = {};
#pragma unroll 8
    for (int i = 0; i < 64; ++i) {
        const float4 a4 = *(const float4*)&At[i * 65 + tr * 4];
        const float4 b4 = *(const float4*)&Wl[i * 64 + tc * 4];
        const float av[4] = {a4.x, a4.y, a4.z, a4.w};
        const float bv[4] = {b4.x, b4.y, b4.z, b4.w};
#pragma unroll
        for (int m = 0; m < 4; ++m)
#pragma unroll
            for (int n = 0; n < 4; ++n) acc[m][n] = fmaf(av[m], bv[n], acc[m][n]);
    }
    const float4 bq = *(const float4*)&bl[tc * 4];
#pragma unroll
    for (int m = 0; m < 4; ++m) {
        float4 o4 = {acc[m][0] + bq.x, acc[m][1] + bq.y, acc[m][2] + bq.z, acc[m][3] + bq.w};
        *(float4*)&out[(r0 + tr * 4 + m) * 64 + tc * 4] = o4;
    }
}

// ---------------- NNConv edge kernel ----------------
// msg[e,o] = sum_{j=0..16} ea'[e,j] * (sum_i h[src_e,i] * Wj[i,o]),  Wj = w_e row j (j=16 -> b_e, ea'=1)
// atomicAdd into agg[dst_e, o].
#define TE 128
__global__ __launch_bounds__(256) void edge_conv(const float* __restrict__ h,
    const float* __restrict__ ea, const int* __restrict__ src, const int* __restrict__ dst,
    const float* __restrict__ we, const float* __restrict__ be, float* __restrict__ agg)
{
    __shared__ float Ht[64 * 129];     // Ht[i*129 + le]; reused as msg[le*64+o] at the end
    __shared__ float Wl[64 * 64];      // [i*64 + o]
    __shared__ float EA[17 * 129];     // [j*129 + le]
    __shared__ int   SR[TE];
    __shared__ int   DS[TE];
    const int tid = threadIdx.x;
    const int e0 = blockIdx.x * TE;

    if (tid < TE) SR[tid] = src[e0 + tid];
    else          DS[tid - TE] = dst[e0 + tid - TE];
    __syncthreads();

    // gather H rows (transposed into LDS)
    for (int q = tid; q < TE * 16; q += 256) {
        const int le = q >> 4, iq = q & 15;
        const float4 v = *(const float4*)(h + (long)SR[le] * 64 + iq * 4);
        const int i = iq * 4;
        Ht[(i + 0) * 129 + le] = v.x; Ht[(i + 1) * 129 + le] = v.y;
        Ht[(i + 2) * 129 + le] = v.z; Ht[(i + 3) * 129 + le] = v.w;
    }
    // edge attrs (+ implicit 1.0 row for bias term)
    for (int s = tid; s < TE * EDIM; s += 256) {
        const int le = s >> 4, j = s & 15;
        EA[j * 129 + le] = ea[(e0 + le) * EDIM + j];
    }
    if (tid < TE) EA[16 * 129 + tid] = 1.0f;

    const int eg = tid >> 3;   // 0..31 -> edges eg*4..eg*4+3
    const int og = tid & 7;    // 0..7  -> outs og*8..og*8+7
    float msg[4][8] = {};

    for (int j = 0; j < 17; ++j) {
        __syncthreads();   // also covers initial staging on j==0
        const float* wsrc = (j < 16) ? (we + j * 4096) : be;
        for (int s = tid; s < 1024; s += 256) ((float4*)Wl)[s] = ((const float4*)wsrc)[s];
        __syncthreads();
        float tmp[4][8] = {};
#pragma unroll 4
        for (int i = 0; i < 64; ++i) {
            const float4 hq = *(const float4*)&Ht[i * 129 + eg * 4];
            const float4 w0 = *(const float4*)&Wl[i * 64 + og * 8];
            const float4 w1 = *(const float4*)&Wl[i * 64 + og * 8 + 4];
            const float hv[4] = {hq.x, hq.y, hq.z, hq.w};
            const float wv[8] = {w0.x, w0.y, w0.z, w0.w, w1.x, w1.y, w1.z, w1.w};
#pragma unroll
            for (int m = 0; m < 4; ++m)
#pragma unroll
                for (int n = 0; n < 8; ++n) tmp[m][n] = fmaf(hv[m], wv[n], tmp[m][n]);
        }
#pragma unroll
        for (int m = 0; m < 4; ++m) {
            const float a = EA[j * 129 + eg * 4 + m];
#pragma unroll
            for (int n = 0; n < 8; ++n) msg[m][n] = fmaf(a, tmp[m][n], msg[m][n]);
        }
    }
    __syncthreads();
    // stash msg in LDS (reuse Ht), then coalesced atomic scatter
#pragma unroll
    for (int m = 0; m < 4; ++m)
#pragma unroll
        for (int n = 0; n < 8; ++n) Ht[(eg * 4 + m) * 64 + og * 8 + n] = msg[m][n];
    __syncthreads();
    for (int s = tid; s < TE * 64; s += 256) {
        const int le = s >> 6, o = s & 63;
        atomicAdd(&agg[(long)DS[le] * 64 + o], Ht[le * 64 + o]);
    }
}

// ---------------- elementwise relu (float4) ----------------
__global__ void relu4(float4* __restrict__ p) {
    const int i = blockIdx.x * 256 + threadIdx.x;
    float4 v = p[i];
    v.x = fmaxf(v.x, 0.f); v.y = fmaxf(v.y, 0.f); v.z = fmaxf(v.z, 0.f); v.w = fmaxf(v.w, 0.f);
    p[i] = v;
}

// ---------------- atom attention scores ----------------
__global__ __launch_bounds__(256) void scores_k(const float* __restrict__ h2,
    const float* __restrict__ w, const float* __restrict__ b, float* __restrict__ sc)
{
    __shared__ float wl[64];
    if (threadIdx.x < 64) wl[threadIdx.x] = w[threadIdx.x];
    __syncthreads();
    const int n = blockIdx.x * 256 + threadIdx.x;
    if (n < N_NODES) {
        float acc = b[0];
        const float4* hp = (const float4*)(h2 + (long)n * 64);
#pragma unroll
        for (int q = 0; q < 16; ++q) {
            const float4 v = hp[q];
            acc = fmaf(v.x, wl[q * 4 + 0], acc); acc = fmaf(v.y, wl[q * 4 + 1], acc);
            acc = fmaf(v.z, wl[q * 4 + 2], acc); acc = fmaf(v.w, wl[q * 4 + 3], acc);
        }
        sc[n] = acc;
    }
}

// ---------------- per-graph softmax over atoms ----------------
__global__ __launch_bounds__(256) void softmax_k(const float* __restrict__ sc, float* __restrict__ attn)
{
    __shared__ float red[256];
    const int g = blockIdx.x, tid = threadIdx.x;
    const float* s = sc + (long)g * NG;
    float m = -1e30f;
    for (int a = tid; a < NG; a += 256) m = fmaxf(m, s[a]);
    red[tid] = m; __syncthreads();
    for (int st = 128; st; st >>= 1) { if (tid < st) red[tid] = fmaxf(red[tid], red[tid + st]); __syncthreads(); }
    const float mx = red[0]; __syncthreads();
    float sum = 0.f;
    for (int a = tid; a < NG; a += 256) sum += expf(s[a] - mx);
    red[tid] = sum; __syncthreads();
    for (int st = 128; st; st >>= 1) { if (tid < st) red[tid] += red[tid + st]; __syncthreads(); }
    const float inv = 1.0f / red[0];
    for (int a = tid; a < NG; a += 256) attn[(long)g * NG + a] = expf(s[a] - mx) * inv;
}

// ---------------- residue pooling + xi concat ----------------
__global__ __launch_bounds__(256) void amino_k(const float* __restrict__ h2,
    const float* __restrict__ attn, const float* __restrict__ aa, float* __restrict__ xi)
{
    const int tid = threadIdx.x;
    const int r = blockIdx.x * 4 + (tid >> 6);   // global residue 0..1599
    const int o = tid & 63;
    const int g = r / NA, ar = r % NA;
    const long base = (long)g * NG + ar * 50;
    float acc = 0.f;
#pragma unroll 10
    for (int a = 0; a < 50; ++a) acc = fmaf(attn[base + a], h2[(base + a) * 64 + o], acc);
    xi[(long)r * FIN + o] = acc;
    for (int s = tid; s < 4 * 95; s += 256) {
        const int lr = s / 95, f = s % 95;
        const int rr = blockIdx.x * 4 + lr;
        xi[(long)rr * FIN + 64 + f] = aa[(long)rr * 95 + f];
    }
}

// ---------------- RI GEMM: [1600,159] @ [159,2688] (+bias on root cols) ----------------
__global__ __launch_bounds__(256) void ri_gemm(const float* __restrict__ xi,
    const float* __restrict__ rootw, const float* __restrict__ initw,
    const float* __restrict__ abias, float* __restrict__ RI)
{
    __shared__ float At[32 * 65];   // [kk*65 + r]
    __shared__ float Bl[32 * 64];   // [kk*64 + cc]
    const int tid = threadIdx.x;
    const int r0 = blockIdx.x * 64, c0 = blockIdx.y * 64;
    const int blk = c0 >> 7;             // 0..20
    const int gb = c0 & 127;             // 0 or 64
    const float* bsrc = (blk < 18) ? (rootw + (long)blk * FIN * 128) : (initw + (long)(blk - 18) * FIN * 128);
    const int tr = tid >> 4, tc = tid & 15;
    float acc[4][4] = {};
    for (int f0 = 0; f0 < FIN; f0 += 32) {
        __syncthreads();
        for (int s = tid; s < 64 * 32; s += 256) {
            const int r = s >> 5, kk = s & 31; const int f = f0 + kk;
            At[kk * 65 + r] = (f < FIN) ? xi[(long)(r0 + r) * FIN + f] : 0.f;
        }
        for (int s = tid; s < 32 * 64; s += 256) {
            const int kk = s >> 6, cc = s & 63; const int f = f0 + kk;
            Bl[s] = (f < FIN) ? bsrc[(long)f * 128 + gb + cc] : 0.f;
        }
        __syncthreads();
#pragma unroll 8
        for (int kk = 0; kk < 32; ++kk) {
            const float4 a4 = *(const float4*)&At[kk * 65 + tr * 4];
            const float4 b4 = *(const float4*)&Bl[kk * 64 + tc * 4];
            const float av[4] = {a4.x, a4.y, a4.z, a4.w};
            const float bv[4] = {b4.x, b4.y, b4.z, b4.w};
#pragma unroll
            for (int m = 0; m < 4; ++m)
#pragma unroll
                for (int n = 0; n < 4; ++n) acc[m][n] = fmaf(av[m], bv[n], acc[m][n]);
        }
    }
    float4 bq = {0.f, 0.f, 0.f, 0.f};
    if (blk < 18) bq = *(const float4*)&abias[c0 + tc * 4];
#pragma unroll
    for (int m = 0; m < 4; ++m) {
        float4 o4 = {acc[m][0] + bq.x, acc[m][1] + bq.y, acc[m][2] + bq.z, acc[m][3] + bq.w};
        *(float4*)&RI[(long)(r0 + tr * 4 + m) * RICOLS + c0 + tc * 4] = o4;
    }
}

// ---------------- ARMA t=0 (elementwise shift + relu) ----------------
__global__ void arma0_k(const float* __restrict__ RI, float* __restrict__ cur)
{
    const int idx = blockIdx.x * 256 + threadIdx.x;  // < 3*1600*128
    const int o = idx & 127;
    const int r = (idx >> 7) % 1600;
    const int k = idx / (1600 * 128);
    const int a = r % NA;
    float v = RI[(long)r * RICOLS + k * 128 + o];
    if (a >= 2) v += RI[(long)(r - 1) * RICOLS + (18 + k) * 128 + o];
    cur[(long)k * 1600 * 128 + r * 128 + o] = fmaxf(v, 0.f);
}

// ---------------- ARMA step t: nxt = relu(shift(cur) @ W[t-1,k] + RI_root[t,k]) ----------------
__global__ __launch_bounds__(256) void arma_step(const float* __restrict__ cur,
    const float* __restrict__ RI, const float* __restrict__ armaw, float* __restrict__ nxt, int t)
{
    __shared__ float Al[64 * 64];   // [r*64 + ff] (per 64-wide f chunk)
    __shared__ float Bl[64 * 64];   // [ff*64 + cc]
    const int tid = threadIdx.x;
    const int r0 = blockIdx.x * 64, c0 = blockIdx.y * 64, k = blockIdx.z;
    const float* W = armaw + (long)((t - 1) * 3 + k) * 128 * 128;
    const int tr = tid >> 4, tc = tid & 15;
    float acc[4][4] = {};
    for (int f0 = 0; f0 < 128; f0 += 64) {
        __syncthreads();
        for (int s = tid; s < 4096; s += 256) {
            const int r = s >> 6, ff = s & 63;
            const int rr = r0 + r; const int a = rr % NA;
            Al[s] = (a >= 2) ? cur[(long)k * 1600 * 128 + (rr - 1) * 128 + f0 + ff] : 0.f;
        }
        for (int s = tid; s < 4096; s += 256) {
            const int ff = s >> 6, cc = s & 63;
            Bl[s] = W[(long)(f0 + ff) * 128 + c0 + cc];
        }
        __syncthreads();
#pragma unroll 8
        for (int ff = 0; ff < 64; ++ff) {
            const float4 b4 = *(const float4*)&Bl[ff * 64 + tc * 4];
            const float bv[4] = {b4.x, b4.y, b4.z, b4.w};
#pragma unroll
            for (int m = 0; m < 4; ++m) {
                const float av = Al[(tr * 4 + m) * 64 + ff];
#pragma unroll
                for (int n = 0; n < 4; ++n) acc[m][n] = fmaf(av, bv[n], acc[m][n]);
            }
        }
    }
#pragma unroll
    for (int m = 0; m < 4; ++m) {
        const int rr = r0 + tr * 4 + m;
        const float4 rq = *(const float4*)&RI[(long)rr * RICOLS + (t * 3 + k) * 128 + c0 + tc * 4];
        float4 o4 = {fmaxf(acc[m][0] + rq.x, 0.f), fmaxf(acc[m][1] + rq.y, 0.f),
                     fmaxf(acc[m][2] + rq.z, 0.f), fmaxf(acc[m][3] + rq.w, 0.f)};
        *(float4*)&nxt[(long)k * 1600 * 128 + rr * 128 + c0 + tc * 4] = o4;
    }
}

// ---------------- final: mean over k + relu, aa-attention, MLP ----------------
__global__ __launch_bounds__(256) void final_k(const float* __restrict__ cur,
    const float* __restrict__ waa, const float* __restrict__ baa,
    const float* __restrict__ w1, const float* __restrict__ b1,
    const float* __restrict__ w2, const float* __restrict__ b2,
    const float* __restrict__ w3, const float* __restrict__ b3,
    const float* __restrict__ w4, const float* __restrict__ b4, float* __restrict__ out)
{
    __shared__ float gl[50 * 129];
    __shared__ float sc[64];
    __shared__ float pl[128];
    __shared__ float h1l[64], h2l[32], h3l[16];
    __shared__ float wl[128];
    const int b = blockIdx.x, tid = threadIdx.x;
    for (int s = tid; s < 50 * 128; s += 256) {
        const int a = s >> 7, o = s & 127;
        const long r = (long)b * 50 + a;
        const float v = (cur[r * 128 + o] + cur[1600 * 128 + r * 128 + o] + cur[2 * 1600 * 128 + r * 128 + o]) * (1.f / 3.f);
        gl[a * 129 + o] = fmaxf(v, 0.f);
    }
    if (tid < 128) wl[tid] = waa[tid];
    __syncthreads();
    if (tid < 50) {
        float acc = baa[0];
        for (int f = 0; f < 128; ++f) acc = fmaf(gl[tid * 129 + f], wl[f], acc);
        sc[tid] = acc;
    }
    __syncthreads();
    if (tid < 64) {
        const float v = (tid < 50) ? sc[tid] : -1e30f;
        float m = v;
        for (int d = 32; d; d >>= 1) m = fmaxf(m, __shfl_xor(m, d));
        const float e = (tid < 50) ? expf(v - m) : 0.f;
        float ssum = e;
        for (int d = 32; d; d >>= 1) ssum += __shfl_xor(ssum, d);
        if (tid < 50) sc[tid] = e / ssum;
    }
    __syncthreads();
    if (tid < 128) {
        float acc = 0.f;
        for (int a = 0; a < 50; ++a) acc = fmaf(sc[a], gl[a * 129 + tid], acc);
        pl[tid] = acc;
    }
    __syncthreads();
    if (tid < 64) {
        float acc = b1[tid];
        for (int f = 0; f < 128; ++f) acc = fmaf(pl[f], w1[f * 64 + tid], acc);
        h1l[tid] = fmaxf(acc, 0.f);
    }
    __syncthreads();
    if (tid < 32) {
        float acc = b2[tid];
        for (int f = 0; f < 64; ++f) acc = fmaf(h1l[f], w2[f * 32 + tid], acc);
        h2l[tid] = fmaxf(acc, 0.f);
    }
    __syncthreads();
    if (tid < 16) {
        float acc = b3[tid];
        for (int f = 0; f < 32; ++f) acc = fmaf(h2l[f], w3[f * 16 + tid], acc);
        h3l[tid] = fmaxf(acc, 0.f);
    }
    __syncthreads();
    if (tid == 0) {
        float acc = b4[0];
        for (int f = 0; f < 16; ++f) acc = fmaf(h3l[f], w4[f], acc);
        out[b] = acc;
    }
}

extern "C" void kernel_launch(void* const* d_in, const int* in_sizes, int n_in,
                              void* d_out, int out_size, void* d_ws, size_t ws_size,
                              hipStream_t stream) {
    const float* x     = (const float*)d_in[0];
    const int*   eidx  = (const int*)d_in[1];
    const float* ea    = (const float*)d_in[2];
    const float* aaf   = (const float*)d_in[4];
    const float* we1   = (const float*)d_in[5];
    const float* be1   = (const float*)d_in[6];
    const float* root1 = (const float*)d_in[7];
    const float* bias1 = (const float*)d_in[8];
    const float* we2   = (const float*)d_in[9];
    const float* be2   = (const float*)d_in[10];
    const float* root2 = (const float*)d_in[11];
    const float* bias2 = (const float*)d_in[12];
    const float* waw   = (const float*)d_in[13];
    const float* wab   = (const float*)d_in[14];
    const float* initw = (const float*)d_in[15];
    const float* armaw = (const float*)d_in[16];
    const float* rootw = (const float*)d_in[17];
    const float* abias = (const float*)d_in[18];
    const float* waa   = (const float*)d_in[19];
    const float* baa   = (const float*)d_in[20];
    const float* w1    = (const float*)d_in[21];
    const float* b1    = (const float*)d_in[22];
    const float* w2    = (const float*)d_in[23];
    const float* b2    = (const float*)d_in[24];
    const float* w3    = (const float*)d_in[25];
    const float* b3    = (const float*)d_in[26];
    const float* w4    = (const float*)d_in[27];
    const float* b4    = (const float*)d_in[28];
    float* out = (float*)d_out;

    const int* src = eidx;
    const int* dst = eidx + N_EDGES;

    char* ws = (char*)d_ws;
    size_t off = 0;
    float* h1     = (float*)(ws + off); off += (size_t)N_NODES * 64 * 4;
    float* h2     = (float*)(ws + off); off += (size_t)N_NODES * 64 * 4;
    float* scores = (float*)(ws + off); off += (size_t)N_NODES * 4;
    float* attn   = (float*)(ws + off); off += (size_t)N_NODES * 4;
    float* xi     = (float*)(ws + off); off += (size_t)1600 * FIN * 4;
    float* RI     = (float*)(ws + off); off += (size_t)1600 * RICOLS * 4;
    float* curA   = (float*)(ws + off); off += (size_t)3 * 1600 * 128 * 4;
    float* curB   = (float*)(ws + off); off += (size_t)3 * 1600 * 128 * 4;

    // conv1: h1 = relu(x@root1 + bias1 + scatter(msg))
    root_gemm<<<N_NODES / 64, 256, 0, stream>>>(x, root1, bias1, h1);
    edge_conv<<<N_EDGES / TE, 256, 0, stream>>>(x, ea, src, dst, we1, be1, h1);
    relu4<<<N_NODES * 64 / 4 / 256, 256, 0, stream>>>((float4*)h1);
    // conv2
    root_gemm<<<N_NODES / 64, 256, 0, stream>>>(h1, root2, bias2, h2);
    edge_conv<<<N_EDGES / TE, 256, 0, stream>>>(h1, ea, src, dst, we2, be2, h2);
    relu4<<<N_NODES * 64 / 4 / 256, 256, 0, stream>>>((float4*)h2);
    // atom attention -> residues -> xi
    scores_k<<<(N_NODES + 255) / 256, 256, 0, stream>>>(h2, waw, wab, scores);
    softmax_k<<<NB, 256, 0, stream>>>(scores, attn);
    amino_k<<<1600 / 4, 256, 0, stream>>>(h2, attn, aaf, xi);
    // ARMA
    ri_gemm<<<dim3(25, 42), 256, 0, stream>>>(xi, rootw, initw, abias, RI);
    arma0_k<<<3 * 1600 * 128 / 256, 256, 0, stream>>>(RI, curA);
    arma_step<<<dim3(25, 2, 3), 256, 0, stream>>>(curA, RI, armaw, curB, 1);
    arma_step<<<dim3(25, 2, 3), 256, 0, stream>>>(curB, RI, armaw, curA, 2);
    arma_step<<<dim3(25, 2, 3), 256, 0, stream>>>(curA, RI, armaw, curB, 3);
    arma_step<<<dim3(25, 2, 3), 256, 0, stream>>>(curB, RI, armaw, curA, 4);
    arma_step<<<dim3(25, 2, 3), 256, 0, stream>>>(curA, RI, armaw, curB, 5);
    // readout + MLP
    final_k<<<NB, 256, 0, stream>>>(curB, waa, baa, w1, b1, w2, b2, w3, b3, w4, b4, out);
}

// Round 3
// 412.255 us; speedup vs baseline: 1.3573x; 1.3573x over previous
//
#include <hip/hip_runtime.h>

#define N_NODES 80000
#define N_EDGES 64000
#define NB      32
#define NG      2500
#define NA      50
#define EDIM    16
#define FIN     159      // H2(64) + AF(95)
#define HG      128
#define RICOLS  2688     // 21 blocks of 128: 18 root(t,k) + 3 init(k)

typedef __attribute__((ext_vector_type(8))) short bf16x8;
typedef __attribute__((ext_vector_type(4))) float f32x4;

__device__ inline ushort rne_bf16(float f) {
    union { float f; unsigned u; } v; v.f = f;
    const unsigned r = v.u + 0x7fffu + ((v.u >> 16) & 1u);
    return (ushort)(r >> 16);
}
__device__ inline float bf16_to_f32(ushort h) {
    union { unsigned u; float f; } v; v.u = ((unsigned)h) << 16;
    return v.f;
}

// ---------------- weight prep: w_e[16,64*64]+b_e[4096] -> bf16 hi/lo fragments ----------------
// Fragment order: Wt[((j*8 + n*2 + kq)*64 + lane)*8 + t] = bf16(W[j][i][o]),
//   o = n*16 + (lane&15), i = kq*32 + (lane>>4)*8 + t   (j==16 -> b_e)
__global__ __launch_bounds__(256) void prep_w(const float* __restrict__ we,
    const float* __restrict__ be, ushort* __restrict__ Whi, ushort* __restrict__ Wlo)
{
    const int idx = blockIdx.x * 256 + threadIdx.x;
    if (idx >= 17 * 8 * 64) return;
    const int l = idx & 63;
    const int slot = (idx >> 6) & 7;
    const int j = idx >> 9;
    const int n = slot >> 1, kq = slot & 1;
    const int o = n * 16 + (l & 15);
    const int i0 = kq * 32 + (l >> 4) * 8;
    ushort th[8], tl[8];
#pragma unroll
    for (int t = 0; t < 8; ++t) {
        const int i = i0 + t;
        const float f = (j < 16) ? we[j * 4096 + i * 64 + o] : be[i * 64 + o];
        const ushort hi = rne_bf16(f);
        th[t] = hi;
        tl[t] = rne_bf16(f - bf16_to_f32(hi));
    }
    *(uint4*)(Whi + (size_t)idx * 8) = *(const uint4*)th;
    *(uint4*)(Wlo + (size_t)idx * 8) = *(const uint4*)tl;
}

// ---------------- root GEMM: out[n,:] = in[n,:] @ W(64x64) + bias ----------------
__global__ __launch_bounds__(256) void root_gemm(const float* __restrict__ in,
    const float* __restrict__ w, const float* __restrict__ bias, float* __restrict__ out)
{
    __shared__ float At[64 * 65];   // At[c*65 + r]
    __shared__ float Wl[64 * 64];   // [i*64 + o]
    __shared__ float bl[64];
    const int tid = threadIdx.x;
    const int r0 = blockIdx.x * 64;
    for (int s = tid; s < 4096; s += 256) { int r = s >> 6, c = s & 63; At[c * 65 + r] = in[(r0 + r) * 64 + c]; }
    for (int s = tid; s < 4096; s += 256) Wl[s] = w[s];
    if (tid < 64) bl[tid] = bias[tid];
    __syncthreads();
    const int tr = tid >> 4, tc = tid & 15;
    float acc[4][4] = {};
#pragma unroll 8
    for (int i = 0; i < 64; ++i) {
        const float4 a4 = *(const float4*)&At[i * 65 + tr * 4];
        const float4 b4 = *(const float4*)&Wl[i * 64 + tc * 4];
        const float av[4] = {a4.x, a4.y, a4.z, a4.w};
        const float bv[4] = {b4.x, b4.y, b4.z, b4.w};
#pragma unroll
        for (int m = 0; m < 4; ++m)
#pragma unroll
            for (int n = 0; n < 4; ++n) acc[m][n] = fmaf(av[m], bv[n], acc[m][n]);
    }
    const float4 bq = *(const float4*)&bl[tc * 4];
#pragma unroll
    for (int m = 0; m < 4; ++m) {
        float4 o4 = {acc[m][0] + bq.x, acc[m][1] + bq.y, acc[m][2] + bq.z, acc[m][3] + bq.w};
        *(float4*)&out[(r0 + tr * 4 + m) * 64 + tc * 4] = o4;
    }
}

// ---------------- NNConv edge kernel, bf16x3 MFMA (error-compensated) ----------------
// msg[e,o] = sum_j ea'[e,j] * (H[e,:] @ Wj)[o];
// H, W split hi+lo bf16; product = Ahi*Bhi + Ahi*Blo + Alo*Bhi (f32 accum).
#define TE 128
__global__ __launch_bounds__(256) void edge_conv_mfma(const float* __restrict__ h,
    const float* __restrict__ ea, const int* __restrict__ src, const int* __restrict__ dst,
    const ushort* __restrict__ Whi, const ushort* __restrict__ Wlo, float* __restrict__ agg)
{
    __shared__ ushort Hh[TE * 64];      // bf16 hi, XOR-swizzled rows
    __shared__ ushort Hl[TE * 64];      // bf16 lo
    __shared__ float  EAt[17 * 132];    // [j][edge]
    __shared__ int    SR[TE], DS[TE];
    const int tid = threadIdx.x;
    const int e0 = blockIdx.x * TE;

    if (tid < TE) SR[tid] = src[e0 + tid];
    else          DS[tid - TE] = dst[e0 + tid - TE];
    __syncthreads();

    // gather H rows -> bf16 hi/lo -> swizzled LDS (byte ^= (row&7)<<4)
    for (int q = tid; q < TE * 16; q += 256) {
        const int le = q >> 4, iq = q & 15;
        const float4 v = *(const float4*)(h + (long)SR[le] * 64 + iq * 4);
        const float fv[4] = {v.x, v.y, v.z, v.w};
        ushort bh[4], bl[4];
#pragma unroll
        for (int t = 0; t < 4; ++t) {
            bh[t] = rne_bf16(fv[t]);
            bl[t] = rne_bf16(fv[t] - bf16_to_f32(bh[t]));
        }
        const int byte = le * 128 + ((iq * 8) ^ ((le & 7) << 4));
        *(ushort4*)((char*)Hh + byte) = *(const ushort4*)bh;
        *(ushort4*)((char*)Hl + byte) = *(const ushort4*)bl;
    }
    // edge attrs transposed [j][e] (+ 1.0 row for bias)
    for (int s = tid; s < TE * 16; s += 256) {
        const int le = s >> 4, j = s & 15;
        EAt[j * 132 + le] = ea[(long)(e0 + le) * 16 + j];
    }
    if (tid < TE) EAt[16 * 132 + tid] = 1.0f;
    __syncthreads();

    const int wv = tid >> 6, l = tid & 63;

    // A fragments to registers once; reused across all 17 j
    bf16x8 ah[2][2], al[2][2];
#pragma unroll
    for (int m = 0; m < 2; ++m)
#pragma unroll
        for (int kq = 0; kq < 2; ++kq) {
            const int row = wv * 32 + m * 16 + (l & 15);
            const int byte = row * 128 + ((kq * 64 + (l >> 4) * 16) ^ ((row & 7) << 4));
            ah[m][kq] = *(const bf16x8*)((const char*)Hh + byte);
            al[m][kq] = *(const bf16x8*)((const char*)Hl + byte);
        }

    f32x4 msg[2][4];
#pragma unroll
    for (int m = 0; m < 2; ++m)
#pragma unroll
        for (int n = 0; n < 4; ++n) msg[m][n] = (f32x4)0.f;

#pragma unroll 1
    for (int j = 0; j < 17; ++j) {
        bf16x8 bh[4][2], bl[4][2];
#pragma unroll
        for (int n = 0; n < 4; ++n)
#pragma unroll
            for (int kq = 0; kq < 2; ++kq) {
                const size_t fo = ((size_t)(j * 8 + n * 2 + kq) * 64 + l) * 8;
                bh[n][kq] = *(const bf16x8*)(Whi + fo);
                bl[n][kq] = *(const bf16x8*)(Wlo + fo);
            }
        f32x4 eam[2];
#pragma unroll
        for (int m = 0; m < 2; ++m)
            eam[m] = *(const f32x4*)&EAt[j * 132 + wv * 32 + m * 16 + (l >> 4) * 4];
#pragma unroll
        for (int m = 0; m < 2; ++m)
#pragma unroll
            for (int n = 0; n < 4; ++n) {
                f32x4 t = __builtin_amdgcn_mfma_f32_16x16x32_bf16(ah[m][0], bh[n][0], (f32x4)0.f, 0, 0, 0);
                t = __builtin_amdgcn_mfma_f32_16x16x32_bf16(ah[m][1], bh[n][1], t, 0, 0, 0);
                t = __builtin_amdgcn_mfma_f32_16x16x32_bf16(ah[m][0], bl[n][0], t, 0, 0, 0);
                t = __builtin_amdgcn_mfma_f32_16x16x32_bf16(ah[m][1], bl[n][1], t, 0, 0, 0);
                t = __builtin_amdgcn_mfma_f32_16x16x32_bf16(al[m][0], bh[n][0], t, 0, 0, 0);
                t = __builtin_amdgcn_mfma_f32_16x16x32_bf16(al[m][1], bh[n][1], t, 0, 0, 0);
                msg[m][n] += eam[m] * t;
            }
    }

    // scatter: C/D layout col=l&15, row=(l>>4)*4+r
#pragma unroll
    for (int m = 0; m < 2; ++m)
#pragma unroll
        for (int n = 0; n < 4; ++n) {
            const int col = n * 16 + (l & 15);
#pragma unroll
            for (int r = 0; r < 4; ++r) {
                const int row = wv * 32 + m * 16 + (l >> 4) * 4 + r;
                atomicAdd(&agg[(long)DS[row] * 64 + col], msg[m][n][r]);
            }
        }
}

// ---------------- elementwise relu (float4) ----------------
__global__ void relu4(float4* __restrict__ p) {
    const int i = blockIdx.x * 256 + threadIdx.x;
    float4 v = p[i];
    v.x = fmaxf(v.x, 0.f); v.y = fmaxf(v.y, 0.f); v.z = fmaxf(v.z, 0.f); v.w = fmaxf(v.w, 0.f);
    p[i] = v;
}

// ---------------- atom attention scores ----------------
__global__ __launch_bounds__(256) void scores_k(const float* __restrict__ h2,
    const float* __restrict__ w, const float* __restrict__ b, float* __restrict__ sc)
{
    __shared__ float wl[64];
    if (threadIdx.x < 64) wl[threadIdx.x] = w[threadIdx.x];
    __syncthreads();
    const int n = blockIdx.x * 256 + threadIdx.x;
    if (n < N_NODES) {
        float acc = b[0];
        const float4* hp = (const float4*)(h2 + (long)n * 64);
#pragma unroll
        for (int q = 0; q < 16; ++q) {
            const float4 v = hp[q];
            acc = fmaf(v.x, wl[q * 4 + 0], acc); acc = fmaf(v.y, wl[q * 4 + 1], acc);
            acc = fmaf(v.z, wl[q * 4 + 2], acc); acc = fmaf(v.w, wl[q * 4 + 3], acc);
        }
        sc[n] = acc;
    }
}

// ---------------- per-graph softmax over atoms ----------------
__global__ __launch_bounds__(256) void softmax_k(const float* __restrict__ sc, float* __restrict__ attn)
{
    __shared__ float red[256];
    const int g = blockIdx.x, tid = threadIdx.x;
    const float* s = sc + (long)g * NG;
    float m = -1e30f;
    for (int a = tid; a < NG; a += 256) m = fmaxf(m, s[a]);
    red[tid] = m; __syncthreads();
    for (int st = 128; st; st >>= 1) { if (tid < st) red[tid] = fmaxf(red[tid], red[tid + st]); __syncthreads(); }
    const float mx = red[0]; __syncthreads();
    float sum = 0.f;
    for (int a = tid; a < NG; a += 256) sum += expf(s[a] - mx);
    red[tid] = sum; __syncthreads();
    for (int st = 128; st; st >>= 1) { if (tid < st) red[tid] += red[tid + st]; __syncthreads(); }
    const float inv = 1.0f / red[0];
    for (int a = tid; a < NG; a += 256) attn[(long)g * NG + a] = expf(s[a] - mx) * inv;
}

// ---------------- residue pooling + xi concat ----------------
__global__ __launch_bounds__(256) void amino_k(const float* __restrict__ h2,
    const float* __restrict__ attn, const float* __restrict__ aa, float* __restrict__ xi)
{
    const int tid = threadIdx.x;
    const int r = blockIdx.x * 4 + (tid >> 6);   // global residue 0..1599
    const int o = tid & 63;
    const int g = r / NA, ar = r % NA;
    const long base = (long)g * NG + ar * 50;
    float acc = 0.f;
#pragma unroll 10
    for (int a = 0; a < 50; ++a) acc = fmaf(attn[base + a], h2[(base + a) * 64 + o], acc);
    xi[(long)r * FIN + o] = acc;
    for (int s = tid; s < 4 * 95; s += 256) {
        const int lr = s / 95, f = s % 95;
        const int rr = blockIdx.x * 4 + lr;
        xi[(long)rr * FIN + 64 + f] = aa[(long)rr * 95 + f];
    }
}

// ---------------- RI GEMM: [1600,159] @ [159,2688] (+bias on root cols) ----------------
__global__ __launch_bounds__(256) void ri_gemm(const float* __restrict__ xi,
    const float* __restrict__ rootw, const float* __restrict__ initw,
    const float* __restrict__ abias, float* __restrict__ RI)
{
    __shared__ float At[32 * 65];   // [kk*65 + r]
    __shared__ float Bl[32 * 64];   // [kk*64 + cc]
    const int tid = threadIdx.x;
    const int r0 = blockIdx.x * 64, c0 = blockIdx.y * 64;
    const int blk = c0 >> 7;             // 0..20
    const int gb = c0 & 127;             // 0 or 64
    const float* bsrc = (blk < 18) ? (rootw + (long)blk * FIN * 128) : (initw + (long)(blk - 18) * FIN * 128);
    const int tr = tid >> 4, tc = tid & 15;
    float acc[4][4] = {};
    for (int f0 = 0; f0 < FIN; f0 += 32) {
        __syncthreads();
        for (int s = tid; s < 64 * 32; s += 256) {
            const int r = s >> 5, kk = s & 31; const int f = f0 + kk;
            At[kk * 65 + r] = (f < FIN) ? xi[(long)(r0 + r) * FIN + f] : 0.f;
        }
        for (int s = tid; s < 32 * 64; s += 256) {
            const int kk = s >> 6, cc = s & 63; const int f = f0 + kk;
            Bl[s] = (f < FIN) ? bsrc[(long)f * 128 + gb + cc] : 0.f;
        }
        __syncthreads();
#pragma unroll 8
        for (int kk = 0; kk < 32; ++kk) {
            const float4 a4 = *(const float4*)&At[kk * 65 + tr * 4];
            const float4 b4 = *(const float4*)&Bl[kk * 64 + tc * 4];
            const float av[4] = {a4.x, a4.y, a4.z, a4.w};
            const float bv[4] = {b4.x, b4.y, b4.z, b4.w};
#pragma unroll
            for (int m = 0; m < 4; ++m)
#pragma unroll
                for (int n = 0; n < 4; ++n) acc[m][n] = fmaf(av[m], bv[n], acc[m][n]);
        }
    }
    float4 bq = {0.f, 0.f, 0.f, 0.f};
    if (blk < 18) bq = *(const float4*)&abias[c0 + tc * 4];
#pragma unroll
    for (int m = 0; m < 4; ++m) {
        float4 o4 = {acc[m][0] + bq.x, acc[m][1] + bq.y, acc[m][2] + bq.z, acc[m][3] + bq.w};
        *(float4*)&RI[(long)(r0 + tr * 4 + m) * RICOLS + c0 + tc * 4] = o4;
    }
}

// ---------------- ARMA t=0 (elementwise shift + relu) ----------------
__global__ void arma0_k(const float* __restrict__ RI, float* __restrict__ cur)
{
    const int idx = blockIdx.x * 256 + threadIdx.x;  // < 3*1600*128
    const int o = idx & 127;
    const int r = (idx >> 7) % 1600;
    const int k = idx / (1600 * 128);
    const int a = r % NA;
    float v = RI[(long)r * RICOLS + k * 128 + o];
    if (a >= 2) v += RI[(long)(r - 1) * RICOLS + (18 + k) * 128 + o];
    cur[(long)k * 1600 * 128 + r * 128 + o] = fmaxf(v, 0.f);
}

// ---------------- ARMA step t: nxt = relu(shift(cur) @ W[t-1,k] + RI_root[t,k]) ----------------
__global__ __launch_bounds__(256) void arma_step(const float* __restrict__ cur,
    const float* __restrict__ RI, const float* __restrict__ armaw, float* __restrict__ nxt, int t)
{
    __shared__ float Al[64 * 64];   // [r*64 + ff] (per 64-wide f chunk)
    __shared__ float Bl[64 * 64];   // [ff*64 + cc]
    const int tid = threadIdx.x;
    const int r0 = blockIdx.x * 64, c0 = blockIdx.y * 64, k = blockIdx.z;
    const float* W = armaw + (long)((t - 1) * 3 + k) * 128 * 128;
    const int tr = tid >> 4, tc = tid & 15;
    float acc[4][4] = {};
    for (int f0 = 0; f0 < 128; f0 += 64) {
        __syncthreads();
        for (int s = tid; s < 4096; s += 256) {
            const int r = s >> 6, ff = s & 63;
            const int rr = r0 + r; const int a = rr % NA;
            Al[s] = (a >= 2) ? cur[(long)k * 1600 * 128 + (rr - 1) * 128 + f0 + ff] : 0.f;
        }
        for (int s = tid; s < 4096; s += 256) {
            const int ff = s >> 6, cc = s & 63;
            Bl[s] = W[(long)(f0 + ff) * 128 + c0 + cc];
        }
        __syncthreads();
#pragma unroll 8
        for (int ff = 0; ff < 64; ++ff) {
            const float4 b4 = *(const float4*)&Bl[ff * 64 + tc * 4];
            const float bv[4] = {b4.x, b4.y, b4.z, b4.w};
#pragma unroll
            for (int m = 0; m < 4; ++m) {
                const float av = Al[(tr * 4 + m) * 64 + ff];
#pragma unroll
                for (int n = 0; n < 4; ++n) acc[m][n] = fmaf(av, bv[n], acc[m][n]);
            }
        }
    }
#pragma unroll
    for (int m = 0; m < 4; ++m) {
        const int rr = r0 + tr * 4 + m;
        const float4 rq = *(const float4*)&RI[(long)rr * RICOLS + (t * 3 + k) * 128 + c0 + tc * 4];
        float4 o4 = {fmaxf(acc[m][0] + rq.x, 0.f), fmaxf(acc[m][1] + rq.y, 0.f),
                     fmaxf(acc[m][2] + rq.z, 0.f), fmaxf(acc[m][3] + rq.w, 0.f)};
        *(float4*)&nxt[(long)k * 1600 * 128 + rr * 128 + c0 + tc * 4] = o4;
    }
}

// ---------------- final: mean over k + relu, aa-attention, MLP ----------------
__global__ __launch_bounds__(256) void final_k(const float* __restrict__ cur,
    const float* __restrict__ waa, const float* __restrict__ baa,
    const float* __restrict__ w1, const float* __restrict__ b1,
    const float* __restrict__ w2, const float* __restrict__ b2,
    const float* __restrict__ w3, const float* __restrict__ b3,
    const float* __restrict__ w4, const float* __restrict__ b4, float* __restrict__ out)
{
    __shared__ float gl[50 * 129];
    __shared__ float sc[64];
    __shared__ float pl[128];
    __shared__ float h1l[64], h2l[32], h3l[16];
    __shared__ float wl[128];
    const int b = blockIdx.x, tid = threadIdx.x;
    for (int s = tid; s < 50 * 128; s += 256) {
        const int a = s >> 7, o = s & 127;
        const long r = (long)b * 50 + a;
        const float v = (cur[r * 128 + o] + cur[1600 * 128 + r * 128 + o] + cur[2 * 1600 * 128 + r * 128 + o]) * (1.f / 3.f);
        gl[a * 129 + o] = fmaxf(v, 0.f);
    }
    if (tid < 128) wl[tid] = waa[tid];
    __syncthreads();
    if (tid < 50) {
        float acc = baa[0];
        for (int f = 0; f < 128; ++f) acc = fmaf(gl[tid * 129 + f], wl[f], acc);
        sc[tid] = acc;
    }
    __syncthreads();
    if (tid < 64) {
        const float v = (tid < 50) ? sc[tid] : -1e30f;
        float m = v;
        for (int d = 32; d; d >>= 1) m = fmaxf(m, __shfl_xor(m, d));
        const float e = (tid < 50) ? expf(v - m) : 0.f;
        float ssum = e;
        for (int d = 32; d; d >>= 1) ssum += __shfl_xor(ssum, d);
        if (tid < 50) sc[tid] = e / ssum;
    }
    __syncthreads();
    if (tid < 128) {
        float acc = 0.f;
        for (int a = 0; a < 50; ++a) acc = fmaf(sc[a], gl[a * 129 + tid], acc);
        pl[tid] = acc;
    }
    __syncthreads();
    if (tid < 64) {
        float acc = b1[tid];
        for (int f = 0; f < 128; ++f) acc = fmaf(pl[f], w1[f * 64 + tid], acc);
        h1l[tid] = fmaxf(acc, 0.f);
    }
    __syncthreads();
    if (tid < 32) {
        float acc = b2[tid];
        for (int f = 0; f < 64; ++f) acc = fmaf(h1l[f], w2[f * 32 + tid], acc);
        h2l[tid] = fmaxf(acc, 0.f);
    }
    __syncthreads();
    if (tid < 16) {
        float acc = b3[tid];
        for (int f = 0; f < 32; ++f) acc = fmaf(h2l[f], w3[f * 16 + tid], acc);
        h3l[tid] = fmaxf(acc, 0.f);
    }
    __syncthreads();
    if (tid == 0) {
        float acc = b4[0];
        for (int f = 0; f < 16; ++f) acc = fmaf(h3l[f], w4[f], acc);
        out[b] = acc;
    }
}

extern "C" void kernel_launch(void* const* d_in, const int* in_sizes, int n_in,
                              void* d_out, int out_size, void* d_ws, size_t ws_size,
                              hipStream_t stream) {
    const float* x     = (const float*)d_in[0];
    const int*   eidx  = (const int*)d_in[1];
    const float* ea    = (const float*)d_in[2];
    const float* aaf   = (const float*)d_in[4];
    const float* we1   = (const float*)d_in[5];
    const float* be1   = (const float*)d_in[6];
    const float* root1 = (const float*)d_in[7];
    const float* bias1 = (const float*)d_in[8];
    const float* we2   = (const float*)d_in[9];
    const float* be2   = (const float*)d_in[10];
    const float* root2 = (const float*)d_in[11];
    const float* bias2 = (const float*)d_in[12];
    const float* waw   = (const float*)d_in[13];
    const float* wab   = (const float*)d_in[14];
    const float* initw = (const float*)d_in[15];
    const float* armaw = (const float*)d_in[16];
    const float* rootw = (const float*)d_in[17];
    const float* abias = (const float*)d_in[18];
    const float* waa   = (const float*)d_in[19];
    const float* baa   = (const float*)d_in[20];
    const float* w1    = (const float*)d_in[21];
    const float* b1    = (const float*)d_in[22];
    const float* w2    = (const float*)d_in[23];
    const float* b2    = (const float*)d_in[24];
    const float* w3    = (const float*)d_in[25];
    const float* b3    = (const float*)d_in[26];
    const float* w4    = (const float*)d_in[27];
    const float* b4    = (const float*)d_in[28];
    float* out = (float*)d_out;

    const int* src = eidx;
    const int* dst = eidx + N_EDGES;

    char* ws = (char*)d_ws;
    size_t off = 0;
    float* h1     = (float*)(ws + off); off += (size_t)N_NODES * 64 * 4;
    float* h2     = (float*)(ws + off); off += (size_t)N_NODES * 64 * 4;
    float* scores = (float*)(ws + off); off += (size_t)N_NODES * 4;
    float* attn   = (float*)(ws + off); off += (size_t)N_NODES * 4;
    float* xi     = (float*)(ws + off); off += (size_t)1600 * FIN * 4;
    float* RI     = (float*)(ws + off); off += (size_t)1600 * RICOLS * 4;
    float* curA   = (float*)(ws + off); off += (size_t)3 * 1600 * 128 * 4;
    float* curB   = (float*)(ws + off); off += (size_t)3 * 1600 * 128 * 4;
    ushort* wt1h  = (ushort*)(ws + off); off += (size_t)17 * 8 * 64 * 8 * 2;
    ushort* wt1l  = (ushort*)(ws + off); off += (size_t)17 * 8 * 64 * 8 * 2;
    ushort* wt2h  = (ushort*)(ws + off); off += (size_t)17 * 8 * 64 * 8 * 2;
    ushort* wt2l  = (ushort*)(ws + off); off += (size_t)17 * 8 * 64 * 8 * 2;

    // one-off weight transform to MFMA fragment layout (bf16 hi/lo)
    prep_w<<<34, 256, 0, stream>>>(we1, be1, wt1h, wt1l);
    prep_w<<<34, 256, 0, stream>>>(we2, be2, wt2h, wt2l);

    // conv1: h1 = relu(x@root1 + bias1 + scatter(msg))
    root_gemm<<<N_NODES / 64, 256, 0, stream>>>(x, root1, bias1, h1);
    edge_conv_mfma<<<N_EDGES / TE, 256, 0, stream>>>(x, ea, src, dst, wt1h, wt1l, h1);
    relu4<<<N_NODES * 64 / 4 / 256, 256, 0, stream>>>((float4*)h1);
    // conv2
    root_gemm<<<N_NODES / 64, 256, 0, stream>>>(h1, root2, bias2, h2);
    edge_conv_mfma<<<N_EDGES / TE, 256, 0, stream>>>(h1, ea, src, dst, wt2h, wt2l, h2);
    relu4<<<N_NODES * 64 / 4 / 256, 256, 0, stream>>>((float4*)h2);
    // atom attention -> residues -> xi
    scores_k<<<(N_NODES + 255) / 256, 256, 0, stream>>>(h2, waw, wab, scores);
    softmax_k<<<NB, 256, 0, stream>>>(scores, attn);
    amino_k<<<1600 / 4, 256, 0, stream>>>(h2, attn, aaf, xi);
    // ARMA
    ri_gemm<<<dim3(25, 42), 256, 0, stream>>>(xi, rootw, initw, abias, RI);
    arma0_k<<<3 * 1600 * 128 / 256, 256, 0, stream>>>(RI, curA);
    arma_step<<<dim3(25, 2, 3), 256, 0, stream>>>(curA, RI, armaw, curB, 1);
    arma_step<<<dim3(25, 2, 3), 256, 0, stream>>>(curB, RI, armaw, curA, 2);
    arma_step<<<dim3(25, 2, 3), 256, 0, stream>>>(curA, RI, armaw, curB, 3);
    arma_step<<<dim3(25, 2, 3), 256, 0, stream>>>(curB, RI, armaw, curA, 4);
    arma_step<<<dim3(25, 2, 3), 256, 0, stream>>>(curA, RI, armaw, curB, 5);
    // readout + MLP
    final_k<<<NB, 256, 0, stream>>>(curB, waa, baa, w1, b1, w2, b2, w3, b3, w4, b4, out);
}